// Round 6
// baseline (352.890 us; speedup 1.0000x reference)
//
#include <hip/hip_runtime.h>
#include <cstdint>
#include <cstddef>

#define NHEAD 4
#define HID 64
#define NCOL 256          // NHEAD*HID
#define INDIM 128
#define PREDDIM 16
#define RELNUM 50
#define NLAYER 3
#define ECHUNK 8192       // edges per chunk-block in bucket build
#define DSHIFT 9          // 512 dsts per bucket
#define DPB 512           // dsts per bucket (src17+type6+dstLow9 = 32 bits)
#define MAXBUCK 256       // >= ceil(N/DPB)=196; LDS hist size
#define MAXCHUNK 512      // >= ceil(E/ECHUNK)=391
#define MLP_NODES 64      // nodes per block in MFMA MLP
#define SPLIT_BLOCKS 32   // NCOL*INDIM / 1024

typedef _Float16 half8 __attribute__((ext_vector_type(8)));
typedef float float4v __attribute__((ext_vector_type(4)));

// ---------------- node scoring MLP via split-f16 MFMA ----------------
// Round-16 (resubmit; round-15 bench was an infra failure, not evidence).
// Occupancy midpoint (256,3). Evidence ledger: (256,2) -> 112 arch VGPR +
// AGPRs ~ >170 total, 2 waves/SIMD, 55us, MfmaUtil 13%, everything idle
// (rounds 11/12/14 all converge here; reg-pinning the B panel changed
// nothing -> B residency is NOT the bottleneck). (256,4) -> 48 VGPR,
// codegen collapse, 133us (round 13). (256,3) targets 170 total regs =
// 3 waves/SIMD, the untested midpoint: +50% TLP to cover the exposed
// latencies, with enough regs for sane codegen. Body is the minimal-
// liveness structure (reduce+store inside mt loop, B loads in a rolled
// ct loop). Accumulation order per output (ct ascending) unchanged ->
// numerics identical. Fragment conventions (verified rounds 5-14):
// A[m=lane&15][k=(lane>>4)*8+j], D col=lane&15, row=(lane>>4)*4+reg.
__global__ __launch_bounds__(256, 3) void mlp_mfma_kernel(
    const float* __restrict__ X, const _Float16* __restrict__ Wh,
    const _Float16* __restrict__ Wl, const float* __restrict__ b1,
    const float* __restrict__ W2, const float* __restrict__ b2,
    float* __restrict__ h0, int N)
{
    __shared__ _Float16 hA[4][4][64][8];   // [mt][ks][slot][j], 16 KB
    __shared__ _Float16 lA[4][4][64][8];

    const int tid = threadIdx.x;
    const int n0  = blockIdx.x * MLP_NODES;

    // ---- stage: thread = (node mg=tid>>2, ks=tid&3): 32 floats -> hi/lo ----
    {
        const int mg = tid >> 2, ks = tid & 3;
        const int gn = min(n0 + mg, N - 1);     // clamp; stores guarded later
        const float4* Xp = reinterpret_cast<const float4*>(X + (size_t)gn * INDIM + ks * 32);
        const int mt = mg >> 4, m = mg & 15;
        #pragma unroll
        for (int qq = 0; qq < 4; qq++) {
            float4 x0 = Xp[qq * 2], x1 = Xp[qq * 2 + 1];
            float xs[8] = { x0.x,x0.y,x0.z,x0.w, x1.x,x1.y,x1.z,x1.w };
            half8 hv, lv;
            #pragma unroll
            for (int j = 0; j < 8; j++) {
                _Float16 hh = (_Float16)xs[j];
                hv[j] = hh;
                lv[j] = (_Float16)((xs[j] - (float)hh) * 2048.0f);
            }
            const int slot = (qq * 16 + m) ^ (2 * ks);   // bank-spread swizzle
            *reinterpret_cast<half8*>(&hA[mt][ks][slot][0]) = hv;
            *reinterpret_cast<half8*>(&lA[mt][ks][slot][0]) = lv;
        }
    }
    __syncthreads();

    const int w    = tid >> 6;             // wave = head
    const int lane = tid & 63;
    const int n16  = lane & 15;
    const int q    = lane >> 4;
    const float bk = b2[w];

    #pragma unroll 1                       // one mt tile finished at a time
    for (int mt = 0; mt < 4; mt++) {
        // A-frags for this tile from LDS (8 half8 = 32 regs)
        half8 ah[4], al[4];
        #pragma unroll
        for (int ks = 0; ks < 4; ks++) {
            const int slot = lane ^ (2 * ks);
            ah[ks] = *reinterpret_cast<const half8*>(&hA[mt][ks][slot][0]);
            al[ks] = *reinterpret_cast<const half8*>(&lA[mt][ks][slot][0]);
        }

        float s[4] = {0.f, 0.f, 0.f, 0.f};

        #pragma unroll 1                   // keeps one ct's B-frags (32 regs)
        for (int ct = 0; ct < 4; ct++) {
            const int c = w * 64 + ct * 16 + n16;
            const _Float16* pb = Wh + (size_t)c * INDIM + q * 8;
            const _Float16* pl = Wl + (size_t)c * INDIM + q * 8;
            half8 bh[4], bl[4];
            #pragma unroll
            for (int ks = 0; ks < 4; ks++) {
                bh[ks] = *reinterpret_cast<const half8*>(pb + ks * 32);
                bl[ks] = *reinterpret_cast<const half8*>(pl + ks * 32);
            }
            const float b1v = b1[c];
            const float w2v = W2[c];

            float4v acc = (float4v){0.f,0.f,0.f,0.f};
            float4v aca = (float4v){0.f,0.f,0.f,0.f};
            float4v acb = (float4v){0.f,0.f,0.f,0.f};
            #pragma unroll
            for (int ks = 0; ks < 4; ks++) {
                acc = __builtin_amdgcn_mfma_f32_16x16x32_f16(ah[ks], bh[ks], acc, 0, 0, 0);
                aca = __builtin_amdgcn_mfma_f32_16x16x32_f16(ah[ks], bl[ks], aca, 0, 0, 0);
                acb = __builtin_amdgcn_mfma_f32_16x16x32_f16(al[ks], bh[ks], acb, 0, 0, 0);
            }
            #pragma unroll
            for (int r = 0; r < 4; r++) {
                float v = acc[r] + (aca[r] + acb[r]) * (1.0f / 2048.0f) + b1v;
                s[r] += fmaxf(v, 0.f) * w2v;
            }
        }

        // ---- reduce over n16 (16 lanes = 16 cols of this head) + store ----
        #pragma unroll
        for (int r = 0; r < 4; r++) {
            float v = s[r];
            v += __shfl_down(v, 8, 16);
            v += __shfl_down(v, 4, 16);
            v += __shfl_down(v, 2, 16);
            v += __shfl_down(v, 1, 16);
            if (n16 == 0) {
                int node = n0 + mt * 16 + q * 4 + r;
                if (node < N) h0[(size_t)node * NHEAD + w] = v + bk;
            }
        }
    }
}

// ---------------- fused: bucket count | attn table | W1 split ----------------
// table_kernel (1 tiny block) and split_w1 (128 small blocks) each
// previously occupied a full serial dispatch while ~255 CUs idled.
// Fuse as heterogeneous blocks of the first kernel: blocks [0,eb) count,
// block eb computes wtab, blocks (eb, eb+SPLIT_BLOCKS] split W1.
// Dependencies preserved: all complete before mlp (Wh/Wl) and agg (wtab).
__global__ __launch_bounds__(1024) void bucket_count_fused_kernel(
    const int* __restrict__ dst, int* __restrict__ blockhist, int E,
    int nbuck, int nb,
    const float* __restrict__ rel_emb, const float* __restrict__ W_pred,
    float* __restrict__ wtab,
    const float* __restrict__ W1, _Float16* __restrict__ Wh,
    _Float16* __restrict__ Wl)
{
    __shared__ int hist[MAXBUCK];
    const int tid = threadIdx.x;
    const int bx  = blockIdx.x;

    if (bx < nb) {
        // ---- bucket count (unchanged) ----
        if (tid < MAXBUCK) hist[tid] = 0;
        __syncthreads();
        const int base = bx * ECHUNK;
        const int end  = min(base + ECHUNK, E);
        const int nvec = (end - base) >> 2;
        const int4* d4p = reinterpret_cast<const int4*>(dst + base);
        for (int g = tid; g < nvec; g += 1024) {
            int4 d = d4p[g];
            atomicAdd(&hist[d.x >> DSHIFT], 1);
            atomicAdd(&hist[d.y >> DSHIFT], 1);
            atomicAdd(&hist[d.z >> DSHIFT], 1);
            atomicAdd(&hist[d.w >> DSHIFT], 1);
        }
        for (int i = base + (nvec << 2) + tid; i < end; i += 1024)
            atomicAdd(&hist[dst[i] >> DSHIFT], 1);
        __syncthreads();
        if (tid < nbuck) blockhist[(size_t)tid * nb + bx] = hist[tid];
    } else if (bx == nb) {
        // ---- attention weight table: 600 entries ----
        const int idx = tid;
        if (idx < NLAYER * RELNUM * NHEAD) {
            int h = idx & 3;
            int qq = idx >> 2;
            int t = qq % RELNUM;
            int l = qq / RELNUM;
            float acc = 0.f;
            #pragma unroll
            for (int p = 0; p < PREDDIM; p++)
                acc = fmaf(rel_emb[t * PREDDIM + p],
                           W_pred[l * PREDDIM * NHEAD + p * NHEAD + h], acc);
            float e = (acc >= 0.f) ? acc : 0.2f * acc;
            wtab[idx] = __expf(e);
        }
    } else {
        // ---- W1 hi/lo f16 split: fp32 = hi + lo/2048 (lo scaled x2048
        // keeps residuals in f16 normal range) ----
        const int i = (bx - nb - 1) * 1024 + tid;   // NCOL*INDIM = 32768
        float v = W1[i];
        _Float16 h = (_Float16)v;
        Wh[i] = h;
        Wl[i] = (_Float16)((v - (float)h) * 2048.0f);
    }
}

// one block per bucket: exclusive scan over its nb chunk counts (nb<=512)
__global__ __launch_bounds__(512) void scan_chunks_kernel(
    const int* __restrict__ blockhist, int* __restrict__ blockbase,
    int* __restrict__ bucket_size, int nb)
{
    __shared__ int s[MAXCHUNK];
    const int b = blockIdx.x;
    const int t = threadIdx.x;
    int v = (t < nb) ? blockhist[(size_t)b * nb + t] : 0;
    s[t] = v;
    __syncthreads();
    for (int off = 1; off < MAXCHUNK; off <<= 1) {
        int u = (t >= off) ? s[t - off] : 0;
        __syncthreads();
        s[t] += u;
        __syncthreads();
    }
    if (t < nb) blockbase[(size_t)b * nb + t] = s[t] - v;   // excl. within bucket
    if (t == MAXCHUNK - 1) bucket_size[b] = s[t];
}

// one small block: exclusive scan of bucket sizes (nbuck <= 256)
__global__ __launch_bounds__(256) void scan_buckets_kernel(
    const int* __restrict__ bucket_size, int* __restrict__ bucket_start, int nbuck)
{
    __shared__ int s[256];
    const int t = threadIdx.x;
    int v = (t < nbuck) ? bucket_size[t] : 0;
    s[t] = v;
    __syncthreads();
    for (int off = 1; off < 256; off <<= 1) {
        int u = (t >= off) ? s[t - off] : 0;
        __syncthreads();
        s[t] += u;
        __syncthreads();
    }
    if (t < nbuck) bucket_start[t] = s[t] - v;
}

__global__ __launch_bounds__(1024) void bucket_scatter_kernel(
    const int* __restrict__ src, const int* __restrict__ dst,
    const int* __restrict__ types, const int* __restrict__ blockbase,
    const int* __restrict__ bucket_start, int* __restrict__ bucketed,
    int E, int nbuck, int nb)
{
    __shared__ int lbase[MAXBUCK];
    __shared__ int cur[MAXBUCK];
    const int tid = threadIdx.x;
    if (tid < MAXBUCK) {
        lbase[tid] = (tid < nbuck)
            ? blockbase[(size_t)tid * nb + blockIdx.x] + bucket_start[tid] : 0;
        cur[tid] = 0;
    }
    __syncthreads();
    const int base = blockIdx.x * ECHUNK;
    const int end  = min(base + ECHUNK, E);
    const int nvec = (end - base) >> 2;
    const int4* s4p = reinterpret_cast<const int4*>(src + base);
    const int4* d4p = reinterpret_cast<const int4*>(dst + base);
    const int4* t4p = reinterpret_cast<const int4*>(types + base);
    for (int g = tid; g < nvec; g += 1024) {
        int4 sv = s4p[g], dv = d4p[g], tv = t4p[g];
        int b, r;
        // src(0..16) | type(17..22) | dstLow(23..31) - sign bit ok, masked on use
        b = dv.x >> DSHIFT; r = atomicAdd(&cur[b], 1);
        bucketed[lbase[b] + r] = sv.x | (tv.x << 17) | ((dv.x & (DPB - 1)) << 23);
        b = dv.y >> DSHIFT; r = atomicAdd(&cur[b], 1);
        bucketed[lbase[b] + r] = sv.y | (tv.y << 17) | ((dv.y & (DPB - 1)) << 23);
        b = dv.z >> DSHIFT; r = atomicAdd(&cur[b], 1);
        bucketed[lbase[b] + r] = sv.z | (tv.z << 17) | ((dv.z & (DPB - 1)) << 23);
        b = dv.w >> DSHIFT; r = atomicAdd(&cur[b], 1);
        bucketed[lbase[b] + r] = sv.w | (tv.w << 17) | ((dv.w & (DPB - 1)) << 23);
    }
    for (int i = base + (nvec << 2) + tid; i < end; i += 1024) {
        int d = dst[i];
        int b = d >> DSHIFT;
        int r = atomicAdd(&cur[b], 1);
        bucketed[lbase[b] + r] = src[i] | (types[i] << 17) | ((d & (DPB - 1)) << 23);
    }
}

// 1024 threads; scan section runs on first DPB=512 threads.
__global__ __launch_bounds__(1024) void bucket_to_csr_kernel(
    const int* __restrict__ bucket_start, const int* __restrict__ bucket_size,
    const int* __restrict__ bucketed, int* __restrict__ sorted,
    int* __restrict__ row_start, int* __restrict__ deg, int N)
{
    __shared__ int cnt[DPB];
    __shared__ int sc[DPB];
    __shared__ int rs[DPB];
    __shared__ int cur[DPB];
    const int tid = threadIdx.x;
    const int b   = blockIdx.x;
    const int d0  = b << DSHIFT;
    const int nd  = min(DPB, N - d0);
    const int s0  = bucket_start[b];
    const int ne  = bucket_size[b];

    if (tid < DPB) { cnt[tid] = 0; cur[tid] = 0; }
    __syncthreads();
    for (int i = tid; i < ne; i += 1024)
        atomicAdd(&cnt[((unsigned)bucketed[s0 + i] >> 23) & (DPB - 1)], 1);
    __syncthreads();
    int v = 0;
    if (tid < DPB) { v = cnt[tid]; sc[tid] = v; }
    __syncthreads();
    for (int off = 1; off < DPB; off <<= 1) {
        int u = (tid < DPB && tid >= off) ? sc[tid - off] : 0;
        __syncthreads();
        if (tid < DPB) sc[tid] += u;
        __syncthreads();
    }
    if (tid < DPB) {
        int ex = sc[tid] - v;
        rs[tid] = s0 + ex;
        if (tid < nd) {
            row_start[d0 + tid] = s0 + ex;
            deg[d0 + tid] = v;
        }
    }
    __syncthreads();
    for (int i = tid; i < ne; i += 1024) {
        int pk = bucketed[s0 + i];
        int d  = ((unsigned)pk >> 23) & (DPB - 1);
        int r  = atomicAdd(&cur[d], 1);
        sorted[rs[d] + r] = pk & 0x7FFFFF;   // src | type<<17
    }
}

// ---------------- per-layer aggregation ----------------
template <int MODE>
__global__ __launch_bounds__(256) void agg_kernel(
    const int* __restrict__ row_start, const int* __restrict__ deg,
    const int* __restrict__ sorted, const float* __restrict__ wt_l,
    const float* __restrict__ hin, float* __restrict__ hout,
    const float* __restrict__ centrality, const float* __restrict__ gamma,
    const float* __restrict__ beta, int N)
{
    __shared__ float wt[RELNUM * NHEAD];
    for (int i = threadIdx.x; i < RELNUM * NHEAD; i += blockDim.x) wt[i] = wt_l[i];
    __syncthreads();

    int gid = blockIdx.x * blockDim.x + threadIdx.x;
    int d = gid >> 2, h = gid & 3;
    if (d >= N) return;

    int b = row_start[d], n = deg[d];
    float num = 0.f, den = 0.f;
    for (int i = 0; i < n; i++) {
        int pk = sorted[b + i];                 // same addr across the quad
        int s = pk & 0x1FFFF;
        int t = pk >> 17;
        float wv = wt[t * NHEAD + h];
        float hv = (MODE == 0) ? hin[(size_t)s * NHEAD + h] : hin[s];
        num = fmaf(wv, hv, num);
        den += wv;
    }
    float r = (n > 0) ? fmaxf(num / den, 0.f) : 0.f;   // relu(segsum(a*h))
    if (MODE == 2) r = (centrality[d] * gamma[h] + beta[h]) * r;
    r += __shfl_xor(r, 1);
    r += __shfl_xor(r, 2);
    r *= 0.25f;
    if (h == 0) {
        if (MODE < 2) hout[d] = r;
        else          hout[d] = (r > 0.f) ? r : 0.01f * r;
    }
}

// ---------------- launch ----------------
extern "C" void kernel_launch(void* const* d_in, const int* in_sizes, int n_in,
                              void* d_out, int out_size, void* d_ws, size_t ws_size,
                              hipStream_t stream)
{
    const float* X          = (const float*)d_in[0];
    const float* centrality = (const float*)d_in[1];
    const float* W1         = (const float*)d_in[2];
    const float* b1         = (const float*)d_in[3];
    const float* W2         = (const float*)d_in[4];
    const float* b2         = (const float*)d_in[5];
    const float* rel_emb    = (const float*)d_in[6];
    const float* W_pred     = (const float*)d_in[7];
    const float* gamma      = (const float*)d_in[8];
    const float* beta       = (const float*)d_in[9];
    const int*   edge_types = (const int*)d_in[10];
    const int*   src        = (const int*)d_in[11];
    const int*   dst        = (const int*)d_in[12];
    float* out = (float*)d_out;

    const int N = in_sizes[1];
    const int E = in_sizes[10];
    const int nbuck = (N + DPB - 1) / DPB;
    const int eb = (E + ECHUNK - 1) / ECHUNK;

    char* ws = (char*)d_ws;
    size_t off = 0;
    auto alloc = [&](size_t bytes) -> void* {
        void* p = ws + off;
        off = (off + bytes + 255) & ~(size_t)255;
        return p;
    };
    int*   deg       = (int*)alloc((size_t)N * 4);
    int*   row_start = (int*)alloc((size_t)N * 4);
    int*   bsize     = (int*)alloc((size_t)MAXBUCK * 4);
    int*   bstart    = (int*)alloc((size_t)MAXBUCK * 4);
    int*   blockhist = (int*)alloc((size_t)nbuck * eb * 4);
    int*   blockbase = (int*)alloc((size_t)nbuck * eb * 4);
    int*   bucketed  = (int*)alloc((size_t)E * 4);
    int*   sorted    = (int*)alloc((size_t)E * 4);
    float* wtab      = (float*)alloc((size_t)NLAYER * RELNUM * NHEAD * 4);
    float* h0        = (float*)alloc((size_t)N * NHEAD * 4);
    float* hs        = (float*)alloc((size_t)N * 4);
    float* hs2       = (float*)alloc((size_t)N * 4);
    _Float16* Wh     = (_Float16*)alloc((size_t)NCOL * INDIM * 2);
    _Float16* Wl     = (_Float16*)alloc((size_t)NCOL * INDIM * 2);
    (void)ws_size; (void)n_in; (void)out_size;

    bucket_count_fused_kernel<<<eb + 1 + SPLIT_BLOCKS, 1024, 0, stream>>>(
        dst, blockhist, E, nbuck, eb, rel_emb, W_pred, wtab, W1, Wh, Wl);
    scan_chunks_kernel<<<nbuck, MAXCHUNK, 0, stream>>>(blockhist, blockbase, bsize, eb);
    scan_buckets_kernel<<<1, 256, 0, stream>>>(bsize, bstart, nbuck);
    bucket_scatter_kernel<<<eb, 1024, 0, stream>>>(src, dst, edge_types, blockbase,
                                                   bstart, bucketed, E, nbuck, eb);
    bucket_to_csr_kernel<<<nbuck, 1024, 0, stream>>>(bstart, bsize, bucketed, sorted,
                                                     row_start, deg, N);

    mlp_mfma_kernel<<<(N + MLP_NODES - 1) / MLP_NODES, 256, 0, stream>>>(
        X, Wh, Wl, b1, W2, b2, h0, N);

    const int ab = (N * NHEAD + 255) / 256;
    agg_kernel<0><<<ab, 256, 0, stream>>>(row_start, deg, sorted, wtab + 0 * RELNUM * NHEAD,
                                          h0, hs, nullptr, nullptr, nullptr, N);
    agg_kernel<1><<<ab, 256, 0, stream>>>(row_start, deg, sorted, wtab + 1 * RELNUM * NHEAD,
                                          hs, hs2, nullptr, nullptr, nullptr, N);
    agg_kernel<2><<<ab, 256, 0, stream>>>(row_start, deg, sorted, wtab + 2 * RELNUM * NHEAD,
                                          hs2, out, centrality, gamma, beta, N);
}

// Round 7
// 352.535 us; speedup vs baseline: 1.0010x; 1.0010x over previous
//
#include <hip/hip_runtime.h>
#include <cstdint>
#include <cstddef>

#define NHEAD 4
#define HID 64
#define NCOL 256          // NHEAD*HID
#define INDIM 128
#define PREDDIM 16
#define RELNUM 50
#define NLAYER 3
#define ECHUNK 8192       // edges per chunk-block in bucket build
#define DSHIFT 9          // 512 dsts per bucket
#define DPB 512           // dsts per bucket (src17+type6+dstLow9 = 32 bits)
#define MAXBUCK 256       // >= ceil(N/DPB)=196; LDS hist size
#define MAXCHUNK 512      // >= ceil(E/ECHUNK)=391
#define MLP_NODES 64      // nodes per block in MFMA MLP
#define SPLIT_BLOCKS 32   // NCOL*INDIM / 1024

typedef _Float16 half8 __attribute__((ext_vector_type(8)));
typedef float float4v __attribute__((ext_vector_type(4)));

// ---------------- node scoring MLP via split-f16 MFMA ----------------
// Round-17: REVERT to the proven (256,2) 112-VGPR form (55us). Ledger:
// (256,2) = 112 VGPR, 55us, MfmaUtil 13% (rounds 11/12/14 — three source
// variants, identical codegen; B-panel reg-pinning changed nothing).
// (256,3) and (256,4) both collapse to 48 VGPR, 122-133us (rounds 13/16).
// Occupancy and load-placement levers are EXHAUSTED on this kernel; 55us
// stands until a structural rewrite. Fragment conventions (verified
// rounds 5-16): A[m=lane&15][k=(lane>>4)*8+j], D col=lane&15,
// row=(lane>>4)*4+reg.
__global__ __launch_bounds__(256, 2) void mlp_mfma_kernel(
    const float* __restrict__ X, const _Float16* __restrict__ Wh,
    const _Float16* __restrict__ Wl, const float* __restrict__ b1,
    const float* __restrict__ W2, const float* __restrict__ b2,
    float* __restrict__ h0, int N)
{
    __shared__ _Float16 hA[4][4][64][8];   // [mt][ks][slot][j], 16 KB
    __shared__ _Float16 lA[4][4][64][8];

    const int tid = threadIdx.x;
    const int n0  = blockIdx.x * MLP_NODES;

    // ---- stage: thread = (node mg=tid>>2, ks=tid&3): 32 floats -> hi/lo ----
    {
        const int mg = tid >> 2, ks = tid & 3;
        const int gn = min(n0 + mg, N - 1);     // clamp; stores guarded later
        const float4* Xp = reinterpret_cast<const float4*>(X + (size_t)gn * INDIM + ks * 32);
        const int mt = mg >> 4, m = mg & 15;
        #pragma unroll
        for (int qq = 0; qq < 4; qq++) {
            float4 x0 = Xp[qq * 2], x1 = Xp[qq * 2 + 1];
            float xs[8] = { x0.x,x0.y,x0.z,x0.w, x1.x,x1.y,x1.z,x1.w };
            half8 hv, lv;
            #pragma unroll
            for (int j = 0; j < 8; j++) {
                _Float16 hh = (_Float16)xs[j];
                hv[j] = hh;
                lv[j] = (_Float16)((xs[j] - (float)hh) * 2048.0f);
            }
            const int slot = (qq * 16 + m) ^ (2 * ks);   // bank-spread swizzle
            *reinterpret_cast<half8*>(&hA[mt][ks][slot][0]) = hv;
            *reinterpret_cast<half8*>(&lA[mt][ks][slot][0]) = lv;
        }
    }
    __syncthreads();

    const int w    = tid >> 6;             // wave = head
    const int lane = tid & 63;
    const int n16  = lane & 15;
    const int q    = lane >> 4;
    const float bk = b2[w];

    #pragma unroll 1                       // one mt tile finished at a time
    for (int mt = 0; mt < 4; mt++) {
        // A-frags for this tile from LDS (8 half8 = 32 regs)
        half8 ah[4], al[4];
        #pragma unroll
        for (int ks = 0; ks < 4; ks++) {
            const int slot = lane ^ (2 * ks);
            ah[ks] = *reinterpret_cast<const half8*>(&hA[mt][ks][slot][0]);
            al[ks] = *reinterpret_cast<const half8*>(&lA[mt][ks][slot][0]);
        }

        float s[4] = {0.f, 0.f, 0.f, 0.f};

        #pragma unroll 1                   // keeps one ct's B-frags (32 regs)
        for (int ct = 0; ct < 4; ct++) {
            const int c = w * 64 + ct * 16 + n16;
            const _Float16* pb = Wh + (size_t)c * INDIM + q * 8;
            const _Float16* pl = Wl + (size_t)c * INDIM + q * 8;
            half8 bh[4], bl[4];
            #pragma unroll
            for (int ks = 0; ks < 4; ks++) {
                bh[ks] = *reinterpret_cast<const half8*>(pb + ks * 32);
                bl[ks] = *reinterpret_cast<const half8*>(pl + ks * 32);
            }
            const float b1v = b1[c];
            const float w2v = W2[c];

            float4v acc = (float4v){0.f,0.f,0.f,0.f};
            float4v aca = (float4v){0.f,0.f,0.f,0.f};
            float4v acb = (float4v){0.f,0.f,0.f,0.f};
            #pragma unroll
            for (int ks = 0; ks < 4; ks++) {
                acc = __builtin_amdgcn_mfma_f32_16x16x32_f16(ah[ks], bh[ks], acc, 0, 0, 0);
                aca = __builtin_amdgcn_mfma_f32_16x16x32_f16(ah[ks], bl[ks], aca, 0, 0, 0);
                acb = __builtin_amdgcn_mfma_f32_16x16x32_f16(al[ks], bh[ks], acb, 0, 0, 0);
            }
            #pragma unroll
            for (int r = 0; r < 4; r++) {
                float v = acc[r] + (aca[r] + acb[r]) * (1.0f / 2048.0f) + b1v;
                s[r] += fmaxf(v, 0.f) * w2v;
            }
        }

        // ---- reduce over n16 (16 lanes = 16 cols of this head) + store ----
        #pragma unroll
        for (int r = 0; r < 4; r++) {
            float v = s[r];
            v += __shfl_down(v, 8, 16);
            v += __shfl_down(v, 4, 16);
            v += __shfl_down(v, 2, 16);
            v += __shfl_down(v, 1, 16);
            if (n16 == 0) {
                int node = n0 + mt * 16 + q * 4 + r;
                if (node < N) h0[(size_t)node * NHEAD + w] = v + bk;
            }
        }
    }
}

// ---------------- fused: bucket count | attn table | W1 split ----------------
// Measured round 6: fusion worth ~3-4us (removes two serial dispatches).
// Blocks [0,eb) count, block eb computes wtab, blocks (eb, eb+SPLIT_BLOCKS]
// split W1. All outputs consumed only by later kernels.
__global__ __launch_bounds__(1024) void bucket_count_fused_kernel(
    const int* __restrict__ dst, int* __restrict__ blockhist, int E,
    int nbuck, int nb,
    const float* __restrict__ rel_emb, const float* __restrict__ W_pred,
    float* __restrict__ wtab,
    const float* __restrict__ W1, _Float16* __restrict__ Wh,
    _Float16* __restrict__ Wl)
{
    __shared__ int hist[MAXBUCK];
    const int tid = threadIdx.x;
    const int bx  = blockIdx.x;

    if (bx < nb) {
        // ---- bucket count (unchanged) ----
        if (tid < MAXBUCK) hist[tid] = 0;
        __syncthreads();
        const int base = bx * ECHUNK;
        const int end  = min(base + ECHUNK, E);
        const int nvec = (end - base) >> 2;
        const int4* d4p = reinterpret_cast<const int4*>(dst + base);
        for (int g = tid; g < nvec; g += 1024) {
            int4 d = d4p[g];
            atomicAdd(&hist[d.x >> DSHIFT], 1);
            atomicAdd(&hist[d.y >> DSHIFT], 1);
            atomicAdd(&hist[d.z >> DSHIFT], 1);
            atomicAdd(&hist[d.w >> DSHIFT], 1);
        }
        for (int i = base + (nvec << 2) + tid; i < end; i += 1024)
            atomicAdd(&hist[dst[i] >> DSHIFT], 1);
        __syncthreads();
        if (tid < nbuck) blockhist[(size_t)tid * nb + bx] = hist[tid];
    } else if (bx == nb) {
        // ---- attention weight table: 600 entries ----
        const int idx = tid;
        if (idx < NLAYER * RELNUM * NHEAD) {
            int h = idx & 3;
            int qq = idx >> 2;
            int t = qq % RELNUM;
            int l = qq / RELNUM;
            float acc = 0.f;
            #pragma unroll
            for (int p = 0; p < PREDDIM; p++)
                acc = fmaf(rel_emb[t * PREDDIM + p],
                           W_pred[l * PREDDIM * NHEAD + p * NHEAD + h], acc);
            float e = (acc >= 0.f) ? acc : 0.2f * acc;
            wtab[idx] = __expf(e);
        }
    } else {
        // ---- W1 hi/lo f16 split: fp32 = hi + lo/2048 (lo scaled x2048
        // keeps residuals in f16 normal range) ----
        const int i = (bx - nb - 1) * 1024 + tid;   // NCOL*INDIM = 32768
        float v = W1[i];
        _Float16 h = (_Float16)v;
        Wh[i] = h;
        Wl[i] = (_Float16)((v - (float)h) * 2048.0f);
    }
}

// one block per bucket: exclusive scan over its nb chunk counts (nb<=512)
__global__ __launch_bounds__(512) void scan_chunks_kernel(
    const int* __restrict__ blockhist, int* __restrict__ blockbase,
    int* __restrict__ bucket_size, int nb)
{
    __shared__ int s[MAXCHUNK];
    const int b = blockIdx.x;
    const int t = threadIdx.x;
    int v = (t < nb) ? blockhist[(size_t)b * nb + t] : 0;
    s[t] = v;
    __syncthreads();
    for (int off = 1; off < MAXCHUNK; off <<= 1) {
        int u = (t >= off) ? s[t - off] : 0;
        __syncthreads();
        s[t] += u;
        __syncthreads();
    }
    if (t < nb) blockbase[(size_t)b * nb + t] = s[t] - v;   // excl. within bucket
    if (t == MAXCHUNK - 1) bucket_size[b] = s[t];
}

// one small block: exclusive scan of bucket sizes (nbuck <= 256)
__global__ __launch_bounds__(256) void scan_buckets_kernel(
    const int* __restrict__ bucket_size, int* __restrict__ bucket_start, int nbuck)
{
    __shared__ int s[256];
    const int t = threadIdx.x;
    int v = (t < nbuck) ? bucket_size[t] : 0;
    s[t] = v;
    __syncthreads();
    for (int off = 1; off < 256; off <<= 1) {
        int u = (t >= off) ? s[t - off] : 0;
        __syncthreads();
        s[t] += u;
        __syncthreads();
    }
    if (t < nbuck) bucket_start[t] = s[t] - v;
}

__global__ __launch_bounds__(1024) void bucket_scatter_kernel(
    const int* __restrict__ src, const int* __restrict__ dst,
    const int* __restrict__ types, const int* __restrict__ blockbase,
    const int* __restrict__ bucket_start, int* __restrict__ bucketed,
    int E, int nbuck, int nb)
{
    __shared__ int lbase[MAXBUCK];
    __shared__ int cur[MAXBUCK];
    const int tid = threadIdx.x;
    if (tid < MAXBUCK) {
        lbase[tid] = (tid < nbuck)
            ? blockbase[(size_t)tid * nb + blockIdx.x] + bucket_start[tid] : 0;
        cur[tid] = 0;
    }
    __syncthreads();
    const int base = blockIdx.x * ECHUNK;
    const int end  = min(base + ECHUNK, E);
    const int nvec = (end - base) >> 2;
    const int4* s4p = reinterpret_cast<const int4*>(src + base);
    const int4* d4p = reinterpret_cast<const int4*>(dst + base);
    const int4* t4p = reinterpret_cast<const int4*>(types + base);
    for (int g = tid; g < nvec; g += 1024) {
        int4 sv = s4p[g], dv = d4p[g], tv = t4p[g];
        int b, r;
        // src(0..16) | type(17..22) | dstLow(23..31) - sign bit ok, masked on use
        b = dv.x >> DSHIFT; r = atomicAdd(&cur[b], 1);
        bucketed[lbase[b] + r] = sv.x | (tv.x << 17) | ((dv.x & (DPB - 1)) << 23);
        b = dv.y >> DSHIFT; r = atomicAdd(&cur[b], 1);
        bucketed[lbase[b] + r] = sv.y | (tv.y << 17) | ((dv.y & (DPB - 1)) << 23);
        b = dv.z >> DSHIFT; r = atomicAdd(&cur[b], 1);
        bucketed[lbase[b] + r] = sv.z | (tv.z << 17) | ((dv.z & (DPB - 1)) << 23);
        b = dv.w >> DSHIFT; r = atomicAdd(&cur[b], 1);
        bucketed[lbase[b] + r] = sv.w | (tv.w << 17) | ((dv.w & (DPB - 1)) << 23);
    }
    for (int i = base + (nvec << 2) + tid; i < end; i += 1024) {
        int d = dst[i];
        int b = d >> DSHIFT;
        int r = atomicAdd(&cur[b], 1);
        bucketed[lbase[b] + r] = src[i] | (types[i] << 17) | ((d & (DPB - 1)) << 23);
    }
}

// 1024 threads; scan section runs on first DPB=512 threads.
__global__ __launch_bounds__(1024) void bucket_to_csr_kernel(
    const int* __restrict__ bucket_start, const int* __restrict__ bucket_size,
    const int* __restrict__ bucketed, int* __restrict__ sorted,
    int* __restrict__ row_start, int* __restrict__ deg, int N)
{
    __shared__ int cnt[DPB];
    __shared__ int sc[DPB];
    __shared__ int rs[DPB];
    __shared__ int cur[DPB];
    const int tid = threadIdx.x;
    const int b   = blockIdx.x;
    const int d0  = b << DSHIFT;
    const int nd  = min(DPB, N - d0);
    const int s0  = bucket_start[b];
    const int ne  = bucket_size[b];

    if (tid < DPB) { cnt[tid] = 0; cur[tid] = 0; }
    __syncthreads();
    for (int i = tid; i < ne; i += 1024)
        atomicAdd(&cnt[((unsigned)bucketed[s0 + i] >> 23) & (DPB - 1)], 1);
    __syncthreads();
    int v = 0;
    if (tid < DPB) { v = cnt[tid]; sc[tid] = v; }
    __syncthreads();
    for (int off = 1; off < DPB; off <<= 1) {
        int u = (tid < DPB && tid >= off) ? sc[tid - off] : 0;
        __syncthreads();
        if (tid < DPB) sc[tid] += u;
        __syncthreads();
    }
    if (tid < DPB) {
        int ex = sc[tid] - v;
        rs[tid] = s0 + ex;
        if (tid < nd) {
            row_start[d0 + tid] = s0 + ex;
            deg[d0 + tid] = v;
        }
    }
    __syncthreads();
    for (int i = tid; i < ne; i += 1024) {
        int pk = bucketed[s0 + i];
        int d  = ((unsigned)pk >> 23) & (DPB - 1);
        int r  = atomicAdd(&cur[d], 1);
        sorted[rs[d] + r] = pk & 0x7FFFFF;   // src | type<<17
    }
}

// ---------------- per-layer aggregation (edge-split quad) ----------------
// Round-17: the old form had 4 threads per dst EACH walking all n edges
// (4E edge-visits/layer), recomputing den identically in all 4 lanes.
// New form: lane j of the quad walks edges j, j+4, ... accumulating
// ALL-4-heads partials (wtab packed as float4 per type), then a 2-step
// __shfl_xor butterfly combines. Edge-visits 4E -> E; per-edge work ~
// halves; TLP unchanged (same grid). Numerics: sum reordering only
// (partial-per-lane then butterfly), ~ulp-level vs 7.6e-6 margin.
template <int MODE>
__global__ __launch_bounds__(256) void agg_kernel(
    const int* __restrict__ row_start, const int* __restrict__ deg,
    const int* __restrict__ sorted, const float* __restrict__ wt_l,
    const float* __restrict__ hin, float* __restrict__ hout,
    const float* __restrict__ centrality, const float* __restrict__ gamma,
    const float* __restrict__ beta, int N)
{
    __shared__ float4 wt4[RELNUM];          // [type] -> 4 heads
    for (int i = threadIdx.x; i < RELNUM; i += blockDim.x)
        wt4[i] = reinterpret_cast<const float4*>(wt_l)[i];
    __syncthreads();

    int gid = blockIdx.x * blockDim.x + threadIdx.x;
    int d = gid >> 2, j = gid & 3;
    if (d >= N) return;

    int b = row_start[d], n = deg[d];
    float n0 = 0.f, n1 = 0.f, n2 = 0.f, n3 = 0.f;
    float d0 = 0.f, d1 = 0.f, d2 = 0.f, d3 = 0.f;
    for (int i = j; i < n; i += 4) {
        int pk = sorted[b + i];             // quad lanes read consecutive addrs
        int s = pk & 0x1FFFF;
        int t = pk >> 17;
        float4 w4 = wt4[t];
        if (MODE == 0) {
            float4 h4 = *reinterpret_cast<const float4*>(hin + (size_t)s * NHEAD);
            n0 = fmaf(w4.x, h4.x, n0); n1 = fmaf(w4.y, h4.y, n1);
            n2 = fmaf(w4.z, h4.z, n2); n3 = fmaf(w4.w, h4.w, n3);
        } else {
            float hv = hin[s];
            n0 = fmaf(w4.x, hv, n0); n1 = fmaf(w4.y, hv, n1);
            n2 = fmaf(w4.z, hv, n2); n3 = fmaf(w4.w, hv, n3);
        }
        d0 += w4.x; d1 += w4.y; d2 += w4.z; d3 += w4.w;
    }

    // quad butterfly: every lane ends with the full 4-head sums
    #pragma unroll
    for (int k = 1; k <= 2; k <<= 1) {
        n0 += __shfl_xor(n0, k); n1 += __shfl_xor(n1, k);
        n2 += __shfl_xor(n2, k); n3 += __shfl_xor(n3, k);
        d0 += __shfl_xor(d0, k); d1 += __shfl_xor(d1, k);
        d2 += __shfl_xor(d2, k); d3 += __shfl_xor(d3, k);
    }

    if (j == 0) {
        float r0 = (n > 0) ? fmaxf(n0 / d0, 0.f) : 0.f;
        float r1 = (n > 0) ? fmaxf(n1 / d1, 0.f) : 0.f;
        float r2 = (n > 0) ? fmaxf(n2 / d2, 0.f) : 0.f;
        float r3 = (n > 0) ? fmaxf(n3 / d3, 0.f) : 0.f;
        if (MODE == 2) {
            float c = centrality[d];
            r0 *= (c * gamma[0] + beta[0]);
            r1 *= (c * gamma[1] + beta[1]);
            r2 *= (c * gamma[2] + beta[2]);
            r3 *= (c * gamma[3] + beta[3]);
        }
        float m = (r0 + r1 + r2 + r3) * 0.25f;
        if (MODE < 2) hout[d] = m;
        else          hout[d] = (m > 0.f) ? m : 0.01f * m;
    }
}

// ---------------- launch ----------------
extern "C" void kernel_launch(void* const* d_in, const int* in_sizes, int n_in,
                              void* d_out, int out_size, void* d_ws, size_t ws_size,
                              hipStream_t stream)
{
    const float* X          = (const float*)d_in[0];
    const float* centrality = (const float*)d_in[1];
    const float* W1         = (const float*)d_in[2];
    const float* b1         = (const float*)d_in[3];
    const float* W2         = (const float*)d_in[4];
    const float* b2         = (const float*)d_in[5];
    const float* rel_emb    = (const float*)d_in[6];
    const float* W_pred     = (const float*)d_in[7];
    const float* gamma      = (const float*)d_in[8];
    const float* beta       = (const float*)d_in[9];
    const int*   edge_types = (const int*)d_in[10];
    const int*   src        = (const int*)d_in[11];
    const int*   dst        = (const int*)d_in[12];
    float* out = (float*)d_out;

    const int N = in_sizes[1];
    const int E = in_sizes[10];
    const int nbuck = (N + DPB - 1) / DPB;
    const int eb = (E + ECHUNK - 1) / ECHUNK;

    char* ws = (char*)d_ws;
    size_t off = 0;
    auto alloc = [&](size_t bytes) -> void* {
        void* p = ws + off;
        off = (off + bytes + 255) & ~(size_t)255;
        return p;
    };
    int*   deg       = (int*)alloc((size_t)N * 4);
    int*   row_start = (int*)alloc((size_t)N * 4);
    int*   bsize     = (int*)alloc((size_t)MAXBUCK * 4);
    int*   bstart    = (int*)alloc((size_t)MAXBUCK * 4);
    int*   blockhist = (int*)alloc((size_t)nbuck * eb * 4);
    int*   blockbase = (int*)alloc((size_t)nbuck * eb * 4);
    int*   bucketed  = (int*)alloc((size_t)E * 4);
    int*   sorted    = (int*)alloc((size_t)E * 4);
    float* wtab      = (float*)alloc((size_t)NLAYER * RELNUM * NHEAD * 4);
    float* h0        = (float*)alloc((size_t)N * NHEAD * 4);
    float* hs        = (float*)alloc((size_t)N * 4);
    float* hs2       = (float*)alloc((size_t)N * 4);
    _Float16* Wh     = (_Float16*)alloc((size_t)NCOL * INDIM * 2);
    _Float16* Wl     = (_Float16*)alloc((size_t)NCOL * INDIM * 2);
    (void)ws_size; (void)n_in; (void)out_size;

    bucket_count_fused_kernel<<<eb + 1 + SPLIT_BLOCKS, 1024, 0, stream>>>(
        dst, blockhist, E, nbuck, eb, rel_emb, W_pred, wtab, W1, Wh, Wl);
    scan_chunks_kernel<<<nbuck, MAXCHUNK, 0, stream>>>(blockhist, blockbase, bsize, eb);
    scan_buckets_kernel<<<1, 256, 0, stream>>>(bsize, bstart, nbuck);
    bucket_scatter_kernel<<<eb, 1024, 0, stream>>>(src, dst, edge_types, blockbase,
                                                   bstart, bucketed, E, nbuck, eb);
    bucket_to_csr_kernel<<<nbuck, 1024, 0, stream>>>(bstart, bsize, bucketed, sorted,
                                                     row_start, deg, N);

    mlp_mfma_kernel<<<(N + MLP_NODES - 1) / MLP_NODES, 256, 0, stream>>>(
        X, Wh, Wl, b1, W2, b2, h0, N);

    const int ab = (N * NHEAD + 255) / 256;
    agg_kernel<0><<<ab, 256, 0, stream>>>(row_start, deg, sorted, wtab + 0 * RELNUM * NHEAD,
                                          h0, hs, nullptr, nullptr, nullptr, N);
    agg_kernel<1><<<ab, 256, 0, stream>>>(row_start, deg, sorted, wtab + 1 * RELNUM * NHEAD,
                                          hs, hs2, nullptr, nullptr, nullptr, N);
    agg_kernel<2><<<ab, 256, 0, stream>>>(row_start, deg, sorted, wtab + 2 * RELNUM * NHEAD,
                                          hs2, out, centrality, gamma, beta, N);
}

// Round 8
// 273.135 us; speedup vs baseline: 1.2920x; 1.2907x over previous
//
#include <hip/hip_runtime.h>
#include <cstdint>
#include <cstddef>

#define NHEAD 4
#define HID 64
#define NCOL 256          // NHEAD*HID
#define INDIM 128
#define PREDDIM 16
#define RELNUM 50
#define NLAYER 3
#define ECHUNK 8192       // edges per chunk-block in bucket build
#define DSHIFT 9          // 512 dsts per bucket
#define DPB 512           // dsts per bucket (src17+type6+dstLow9 = 32 bits)
#define MAXBUCK 256       // >= ceil(N/DPB)=196; LDS hist size
#define MAXCHUNK 512      // >= ceil(E/ECHUNK)=391
#define SPLIT_BLOCKS 32   // NCOL*INDIM / 1024
#define MLP_GRID 512      // persistent: 2 blocks/CU x 256 CU, all resident

typedef _Float16 half8 __attribute__((ext_vector_type(8)));
typedef float float4v __attribute__((ext_vector_type(4)));
typedef const __attribute__((address_space(1))) void gvoid_t;
typedef __attribute__((address_space(3))) void lvoid_t;

// ---------------- node scoring MLP: pipelined split-f16 MFMA ----------------
// Round-18. CODEGEN LEDGER (hard-won): the 112-VGPR/55us mode needs the
// round-4 body = {B-panel loads issued up front + asm reg-pin + fully
// unrolled ct loop}. The "minimal-liveness" body (rolled ct with loads
// inside, per-tile reduce) collapses to 48 VGPR/122us at ANY launch bound
// (rounds 13/16/17 — launch_bounds was a confound, body structure is the
// trigger). DO NOT remove the pin or re-roll ct.
// Round-7 analysis: dur ~= hbm_bytes/bw (27.8MB @ ~500GB/s = 55us) ->
// X-fetch-bound at ~8% duty: stage and compute strictly alternate across
// a barrier. This version overlaps them: persistent blocks (grid 512, all
// resident), double-buffered LDS (2x32KB), X staged RAW f32 via
// global_load_lds(16B); stage(t+1) issues before compute(t) (T3 2-phase).
// hi/lo split moved to the LDS->reg read: same formula, same MFMA order ->
// numerically identical. XOR-16B swizzle on f32 rows kills the 16-way
// ds_read_b128 bank conflict; global_load_lds keeps a LINEAR LDS dest and
// applies the inverse swizzle to the per-lane GLOBAL address (m104/m173).
// Fragment conventions (verified rounds 5-17):
// A[m=lane&15][k=(lane>>4)*8+j], D col=lane&15, row=(lane>>4)*4+reg.
__global__ __launch_bounds__(256, 2) void mlp_mfma_kernel(
    const float* __restrict__ X, const _Float16* __restrict__ Wh,
    const _Float16* __restrict__ Wl, const float* __restrict__ b1,
    const float* __restrict__ W2, const float* __restrict__ b2,
    float* __restrict__ h0, int N)
{
    __shared__ float Xs[2][64][128];       // 64 KB double buffer (raw f32)

    const int tid  = threadIdx.x;
    const int w    = tid >> 6;             // wave = head
    const int lane = tid & 63;
    const int n16  = lane & 15;
    const int q    = lane >> 4;
    const int swzm = (n16 & 7) << 4;       // read-side 16B XOR swizzle

    // ---- B panel: issue loads up front, then PIN (round-4 proven form) ----
    half8 bh[4][4], bl[4][4];
    float b1v[4], w2v[4];
    #pragma unroll
    for (int ct = 0; ct < 4; ct++) {
        const int c = w * 64 + ct * 16 + n16;
        const _Float16* pb = Wh + (size_t)c * INDIM + q * 8;
        const _Float16* pl = Wl + (size_t)c * INDIM + q * 8;
        #pragma unroll
        for (int ks = 0; ks < 4; ks++) {
            bh[ct][ks] = *reinterpret_cast<const half8*>(pb + ks * 32);
            bl[ct][ks] = *reinterpret_cast<const half8*>(pl + ks * 32);
        }
        b1v[ct] = b1[c];
        w2v[ct] = W2[c];
    }
    #pragma unroll
    for (int ct = 0; ct < 4; ct++) {
        #pragma unroll
        for (int ks = 0; ks < 4; ks++)
            asm volatile("" : "+v"(bh[ct][ks]), "+v"(bl[ct][ks]));
        asm volatile("" : "+v"(b1v[ct]), "+v"(w2v[ct]));
    }

    const float bk = b2[w];
    const int ntiles = (N + 63) >> 6;

    // ---- async stage: 32KB tile of X (f32, rows linear, cols pre-swizzled
    // on the GLOBAL side so the linear LDS write lands swizzled) ----
    auto stage = [&](int tile, int buf) {
        #pragma unroll
        for (int i = 0; i < 8; i++) {
            const int lds_off = i * 4096 + w * 1024 + lane * 16;
            const int node = lds_off >> 9;               // /512B per row
            const int scol = (lds_off & 511) ^ ((node & 7) << 4);
            const int gn = min(tile * 64 + node, N - 1); // clamp tail
            const char* gsrc = (const char*)X + (size_t)gn * 512 + scol;
            char* ldst = (char*)(&Xs[buf][0][0]) + lds_off;
            __builtin_amdgcn_global_load_lds((gvoid_t*)gsrc, (lvoid_t*)ldst,
                                             16, 0, 0);
        }
    };

    int tile = blockIdx.x;
    if (tile >= ntiles) return;
    int buf = 0;
    stage(tile, 0);
    asm volatile("s_waitcnt vmcnt(0)" ::: "memory");
    __syncthreads();

    while (true) {
        const int nxt = tile + MLP_GRID;
        if (nxt < ntiles) stage(nxt, buf ^ 1);   // async, flies under MFMAs

        // ---- compute this tile from Xs[buf] ----
        #pragma unroll 1
        for (int mt = 0; mt < 4; mt++) {
            const char* rowp = (const char*)(&Xs[buf][mt * 16 + n16][0]);
            half8 ah[4], al[4];
            #pragma unroll
            for (int ks = 0; ks < 4; ks++) {
                const int cb0 = ks * 128 + q * 32;
                float4v r0 = *reinterpret_cast<const float4v*>(rowp + (cb0 ^ swzm));
                float4v r1 = *reinterpret_cast<const float4v*>(rowp + ((cb0 + 16) ^ swzm));
                #pragma unroll
                for (int j = 0; j < 4; j++) {
                    float x = r0[j];
                    _Float16 hh = (_Float16)x;
                    ah[ks][j] = hh;
                    al[ks][j] = (_Float16)((x - (float)hh) * 2048.0f);
                    x = r1[j];
                    hh = (_Float16)x;
                    ah[ks][4 + j] = hh;
                    al[ks][4 + j] = (_Float16)((x - (float)hh) * 2048.0f);
                }
            }

            float s[4] = {0.f, 0.f, 0.f, 0.f};
            #pragma unroll
            for (int ct = 0; ct < 4; ct++) {
                float4v acc = (float4v){0.f,0.f,0.f,0.f};
                float4v aca = (float4v){0.f,0.f,0.f,0.f};
                float4v acb = (float4v){0.f,0.f,0.f,0.f};
                #pragma unroll
                for (int ks = 0; ks < 4; ks++) {
                    acc = __builtin_amdgcn_mfma_f32_16x16x32_f16(ah[ks], bh[ct][ks], acc, 0, 0, 0);
                    aca = __builtin_amdgcn_mfma_f32_16x16x32_f16(ah[ks], bl[ct][ks], aca, 0, 0, 0);
                    acb = __builtin_amdgcn_mfma_f32_16x16x32_f16(al[ks], bh[ct][ks], acb, 0, 0, 0);
                }
                #pragma unroll
                for (int r = 0; r < 4; r++) {
                    float v = acc[r] + (aca[r] + acb[r]) * (1.0f / 2048.0f) + b1v[ct];
                    s[r] += fmaxf(v, 0.f) * w2v[ct];
                }
            }

            #pragma unroll
            for (int r = 0; r < 4; r++) {
                float v = s[r];
                v += __shfl_down(v, 8, 16);
                v += __shfl_down(v, 4, 16);
                v += __shfl_down(v, 2, 16);
                v += __shfl_down(v, 1, 16);
                if (n16 == 0) {
                    int node = tile * 64 + mt * 16 + q * 4 + r;
                    if (node < N) h0[(size_t)node * NHEAD + w] = v + bk;
                }
            }
        }

        if (nxt >= ntiles) break;
        asm volatile("s_waitcnt vmcnt(0)" ::: "memory");  // stage landed
        __syncthreads();                                   // all waves done w/ buf
        tile = nxt;
        buf ^= 1;
    }
}

// ---------------- fused: bucket count | attn table | W1 split ----------------
// Measured round 6: fusion worth ~3-4us (removes two serial dispatches).
__global__ __launch_bounds__(1024) void bucket_count_fused_kernel(
    const int* __restrict__ dst, int* __restrict__ blockhist, int E,
    int nbuck, int nb,
    const float* __restrict__ rel_emb, const float* __restrict__ W_pred,
    float* __restrict__ wtab,
    const float* __restrict__ W1, _Float16* __restrict__ Wh,
    _Float16* __restrict__ Wl)
{
    __shared__ int hist[MAXBUCK];
    const int tid = threadIdx.x;
    const int bx  = blockIdx.x;

    if (bx < nb) {
        if (tid < MAXBUCK) hist[tid] = 0;
        __syncthreads();
        const int base = bx * ECHUNK;
        const int end  = min(base + ECHUNK, E);
        const int nvec = (end - base) >> 2;
        const int4* d4p = reinterpret_cast<const int4*>(dst + base);
        for (int g = tid; g < nvec; g += 1024) {
            int4 d = d4p[g];
            atomicAdd(&hist[d.x >> DSHIFT], 1);
            atomicAdd(&hist[d.y >> DSHIFT], 1);
            atomicAdd(&hist[d.z >> DSHIFT], 1);
            atomicAdd(&hist[d.w >> DSHIFT], 1);
        }
        for (int i = base + (nvec << 2) + tid; i < end; i += 1024)
            atomicAdd(&hist[dst[i] >> DSHIFT], 1);
        __syncthreads();
        if (tid < nbuck) blockhist[(size_t)tid * nb + bx] = hist[tid];
    } else if (bx == nb) {
        const int idx = tid;
        if (idx < NLAYER * RELNUM * NHEAD) {
            int h = idx & 3;
            int qq = idx >> 2;
            int t = qq % RELNUM;
            int l = qq / RELNUM;
            float acc = 0.f;
            #pragma unroll
            for (int p = 0; p < PREDDIM; p++)
                acc = fmaf(rel_emb[t * PREDDIM + p],
                           W_pred[l * PREDDIM * NHEAD + p * NHEAD + h], acc);
            float e = (acc >= 0.f) ? acc : 0.2f * acc;
            wtab[idx] = __expf(e);
        }
    } else {
        // W1 hi/lo split: fp32 = hi + lo/2048 (lo x2048 keeps f16 normal)
        const int i = (bx - nb - 1) * 1024 + tid;   // NCOL*INDIM = 32768
        float v = W1[i];
        _Float16 h = (_Float16)v;
        Wh[i] = h;
        Wl[i] = (_Float16)((v - (float)h) * 2048.0f);
    }
}

// one block per bucket: exclusive scan over its nb chunk counts (nb<=512)
__global__ __launch_bounds__(512) void scan_chunks_kernel(
    const int* __restrict__ blockhist, int* __restrict__ blockbase,
    int* __restrict__ bucket_size, int nb)
{
    __shared__ int s[MAXCHUNK];
    const int b = blockIdx.x;
    const int t = threadIdx.x;
    int v = (t < nb) ? blockhist[(size_t)b * nb + t] : 0;
    s[t] = v;
    __syncthreads();
    for (int off = 1; off < MAXCHUNK; off <<= 1) {
        int u = (t >= off) ? s[t - off] : 0;
        __syncthreads();
        s[t] += u;
        __syncthreads();
    }
    if (t < nb) blockbase[(size_t)b * nb + t] = s[t] - v;   // excl. within bucket
    if (t == MAXCHUNK - 1) bucket_size[b] = s[t];
}

// one small block: exclusive scan of bucket sizes (nbuck <= 256)
__global__ __launch_bounds__(256) void scan_buckets_kernel(
    const int* __restrict__ bucket_size, int* __restrict__ bucket_start, int nbuck)
{
    __shared__ int s[256];
    const int t = threadIdx.x;
    int v = (t < nbuck) ? bucket_size[t] : 0;
    s[t] = v;
    __syncthreads();
    for (int off = 1; off < 256; off <<= 1) {
        int u = (t >= off) ? s[t - off] : 0;
        __syncthreads();
        s[t] += u;
        __syncthreads();
    }
    if (t < nbuck) bucket_start[t] = s[t] - v;
}

__global__ __launch_bounds__(1024) void bucket_scatter_kernel(
    const int* __restrict__ src, const int* __restrict__ dst,
    const int* __restrict__ types, const int* __restrict__ blockbase,
    const int* __restrict__ bucket_start, int* __restrict__ bucketed,
    int E, int nbuck, int nb)
{
    __shared__ int lbase[MAXBUCK];
    __shared__ int cur[MAXBUCK];
    const int tid = threadIdx.x;
    if (tid < MAXBUCK) {
        lbase[tid] = (tid < nbuck)
            ? blockbase[(size_t)tid * nb + blockIdx.x] + bucket_start[tid] : 0;
        cur[tid] = 0;
    }
    __syncthreads();
    const int base = blockIdx.x * ECHUNK;
    const int end  = min(base + ECHUNK, E);
    const int nvec = (end - base) >> 2;
    const int4* s4p = reinterpret_cast<const int4*>(src + base);
    const int4* d4p = reinterpret_cast<const int4*>(dst + base);
    const int4* t4p = reinterpret_cast<const int4*>(types + base);
    for (int g = tid; g < nvec; g += 1024) {
        int4 sv = s4p[g], dv = d4p[g], tv = t4p[g];
        int b, r;
        // src(0..16) | type(17..22) | dstLow(23..31) - sign bit ok, masked on use
        b = dv.x >> DSHIFT; r = atomicAdd(&cur[b], 1);
        bucketed[lbase[b] + r] = sv.x | (tv.x << 17) | ((dv.x & (DPB - 1)) << 23);
        b = dv.y >> DSHIFT; r = atomicAdd(&cur[b], 1);
        bucketed[lbase[b] + r] = sv.y | (tv.y << 17) | ((dv.y & (DPB - 1)) << 23);
        b = dv.z >> DSHIFT; r = atomicAdd(&cur[b], 1);
        bucketed[lbase[b] + r] = sv.z | (tv.z << 17) | ((dv.z & (DPB - 1)) << 23);
        b = dv.w >> DSHIFT; r = atomicAdd(&cur[b], 1);
        bucketed[lbase[b] + r] = sv.w | (tv.w << 17) | ((dv.w & (DPB - 1)) << 23);
    }
    for (int i = base + (nvec << 2) + tid; i < end; i += 1024) {
        int d = dst[i];
        int b = d >> DSHIFT;
        int r = atomicAdd(&cur[b], 1);
        bucketed[lbase[b] + r] = src[i] | (types[i] << 17) | ((d & (DPB - 1)) << 23);
    }
}

// 1024 threads; scan section runs on first DPB=512 threads.
__global__ __launch_bounds__(1024) void bucket_to_csr_kernel(
    const int* __restrict__ bucket_start, const int* __restrict__ bucket_size,
    const int* __restrict__ bucketed, int* __restrict__ sorted,
    int* __restrict__ row_start, int* __restrict__ deg, int N)
{
    __shared__ int cnt[DPB];
    __shared__ int sc[DPB];
    __shared__ int rs[DPB];
    __shared__ int cur[DPB];
    const int tid = threadIdx.x;
    const int b   = blockIdx.x;
    const int d0  = b << DSHIFT;
    const int nd  = min(DPB, N - d0);
    const int s0  = bucket_start[b];
    const int ne  = bucket_size[b];

    if (tid < DPB) { cnt[tid] = 0; cur[tid] = 0; }
    __syncthreads();
    for (int i = tid; i < ne; i += 1024)
        atomicAdd(&cnt[((unsigned)bucketed[s0 + i] >> 23) & (DPB - 1)], 1);
    __syncthreads();
    int v = 0;
    if (tid < DPB) { v = cnt[tid]; sc[tid] = v; }
    __syncthreads();
    for (int off = 1; off < DPB; off <<= 1) {
        int u = (tid < DPB && tid >= off) ? sc[tid - off] : 0;
        __syncthreads();
        if (tid < DPB) sc[tid] += u;
        __syncthreads();
    }
    if (tid < DPB) {
        int ex = sc[tid] - v;
        rs[tid] = s0 + ex;
        if (tid < nd) {
            row_start[d0 + tid] = s0 + ex;
            deg[d0 + tid] = v;
        }
    }
    __syncthreads();
    for (int i = tid; i < ne; i += 1024) {
        int pk = bucketed[s0 + i];
        int d  = ((unsigned)pk >> 23) & (DPB - 1);
        int r  = atomicAdd(&cur[d], 1);
        sorted[rs[d] + r] = pk & 0x7FFFFF;   // src | type<<17
    }
}

// ---------------- per-layer aggregation (edge-split quad) ----------------
// Round-7 measured: edge-split (4E->E visits) was time-neutral -> agg is
// latency/issue-bound, not instruction-bound. Kept (strictly less work).
template <int MODE>
__global__ __launch_bounds__(256) void agg_kernel(
    const int* __restrict__ row_start, const int* __restrict__ deg,
    const int* __restrict__ sorted, const float* __restrict__ wt_l,
    const float* __restrict__ hin, float* __restrict__ hout,
    const float* __restrict__ centrality, const float* __restrict__ gamma,
    const float* __restrict__ beta, int N)
{
    __shared__ float4 wt4[RELNUM];          // [type] -> 4 heads
    for (int i = threadIdx.x; i < RELNUM; i += blockDim.x)
        wt4[i] = reinterpret_cast<const float4*>(wt_l)[i];
    __syncthreads();

    int gid = blockIdx.x * blockDim.x + threadIdx.x;
    int d = gid >> 2, j = gid & 3;
    if (d >= N) return;

    int b = row_start[d], n = deg[d];
    float n0 = 0.f, n1 = 0.f, n2 = 0.f, n3 = 0.f;
    float d0 = 0.f, d1 = 0.f, d2 = 0.f, d3 = 0.f;
    for (int i = j; i < n; i += 4) {
        int pk = sorted[b + i];
        int s = pk & 0x1FFFF;
        int t = pk >> 17;
        float4 w4 = wt4[t];
        if (MODE == 0) {
            float4 h4 = *reinterpret_cast<const float4*>(hin + (size_t)s * NHEAD);
            n0 = fmaf(w4.x, h4.x, n0); n1 = fmaf(w4.y, h4.y, n1);
            n2 = fmaf(w4.z, h4.z, n2); n3 = fmaf(w4.w, h4.w, n3);
        } else {
            float hv = hin[s];
            n0 = fmaf(w4.x, hv, n0); n1 = fmaf(w4.y, hv, n1);
            n2 = fmaf(w4.z, hv, n2); n3 = fmaf(w4.w, hv, n3);
        }
        d0 += w4.x; d1 += w4.y; d2 += w4.z; d3 += w4.w;
    }

    #pragma unroll
    for (int k = 1; k <= 2; k <<= 1) {
        n0 += __shfl_xor(n0, k); n1 += __shfl_xor(n1, k);
        n2 += __shfl_xor(n2, k); n3 += __shfl_xor(n3, k);
        d0 += __shfl_xor(d0, k); d1 += __shfl_xor(d1, k);
        d2 += __shfl_xor(d2, k); d3 += __shfl_xor(d3, k);
    }

    if (j == 0) {
        float r0 = (n > 0) ? fmaxf(n0 / d0, 0.f) : 0.f;
        float r1 = (n > 0) ? fmaxf(n1 / d1, 0.f) : 0.f;
        float r2 = (n > 0) ? fmaxf(n2 / d2, 0.f) : 0.f;
        float r3 = (n > 0) ? fmaxf(n3 / d3, 0.f) : 0.f;
        if (MODE == 2) {
            float c = centrality[d];
            r0 *= (c * gamma[0] + beta[0]);
            r1 *= (c * gamma[1] + beta[1]);
            r2 *= (c * gamma[2] + beta[2]);
            r3 *= (c * gamma[3] + beta[3]);
        }
        float m = (r0 + r1 + r2 + r3) * 0.25f;
        if (MODE < 2) hout[d] = m;
        else          hout[d] = (m > 0.f) ? m : 0.01f * m;
    }
}

// ---------------- launch ----------------
extern "C" void kernel_launch(void* const* d_in, const int* in_sizes, int n_in,
                              void* d_out, int out_size, void* d_ws, size_t ws_size,
                              hipStream_t stream)
{
    const float* X          = (const float*)d_in[0];
    const float* centrality = (const float*)d_in[1];
    const float* W1         = (const float*)d_in[2];
    const float* b1         = (const float*)d_in[3];
    const float* W2         = (const float*)d_in[4];
    const float* b2         = (const float*)d_in[5];
    const float* rel_emb    = (const float*)d_in[6];
    const float* W_pred     = (const float*)d_in[7];
    const float* gamma      = (const float*)d_in[8];
    const float* beta       = (const float*)d_in[9];
    const int*   edge_types = (const int*)d_in[10];
    const int*   src        = (const int*)d_in[11];
    const int*   dst        = (const int*)d_in[12];
    float* out = (float*)d_out;

    const int N = in_sizes[1];
    const int E = in_sizes[10];
    const int nbuck = (N + DPB - 1) / DPB;
    const int eb = (E + ECHUNK - 1) / ECHUNK;

    char* ws = (char*)d_ws;
    size_t off = 0;
    auto alloc = [&](size_t bytes) -> void* {
        void* p = ws + off;
        off = (off + bytes + 255) & ~(size_t)255;
        return p;
    };
    int*   deg       = (int*)alloc((size_t)N * 4);
    int*   row_start = (int*)alloc((size_t)N * 4);
    int*   bsize     = (int*)alloc((size_t)MAXBUCK * 4);
    int*   bstart    = (int*)alloc((size_t)MAXBUCK * 4);
    int*   blockhist = (int*)alloc((size_t)nbuck * eb * 4);
    int*   blockbase = (int*)alloc((size_t)nbuck * eb * 4);
    int*   bucketed  = (int*)alloc((size_t)E * 4);
    int*   sorted    = (int*)alloc((size_t)E * 4);
    float* wtab      = (float*)alloc((size_t)NLAYER * RELNUM * NHEAD * 4);
    float* h0        = (float*)alloc((size_t)N * NHEAD * 4);
    float* hs        = (float*)alloc((size_t)N * 4);
    float* hs2       = (float*)alloc((size_t)N * 4);
    _Float16* Wh     = (_Float16*)alloc((size_t)NCOL * INDIM * 2);
    _Float16* Wl     = (_Float16*)alloc((size_t)NCOL * INDIM * 2);
    (void)ws_size; (void)n_in; (void)out_size;

    bucket_count_fused_kernel<<<eb + 1 + SPLIT_BLOCKS, 1024, 0, stream>>>(
        dst, blockhist, E, nbuck, eb, rel_emb, W_pred, wtab, W1, Wh, Wl);
    scan_chunks_kernel<<<nbuck, MAXCHUNK, 0, stream>>>(blockhist, blockbase, bsize, eb);
    scan_buckets_kernel<<<1, 256, 0, stream>>>(bsize, bstart, nbuck);
    bucket_scatter_kernel<<<eb, 1024, 0, stream>>>(src, dst, edge_types, blockbase,
                                                   bstart, bucketed, E, nbuck, eb);
    bucket_to_csr_kernel<<<nbuck, 1024, 0, stream>>>(bstart, bsize, bucketed, sorted,
                                                     row_start, deg, N);

    mlp_mfma_kernel<<<MLP_GRID, 256, 0, stream>>>(X, Wh, Wl, b1, W2, b2, h0, N);

    const int ab = (N * NHEAD + 255) / 256;
    agg_kernel<0><<<ab, 256, 0, stream>>>(row_start, deg, sorted, wtab + 0 * RELNUM * NHEAD,
                                          h0, hs, nullptr, nullptr, nullptr, N);
    agg_kernel<1><<<ab, 256, 0, stream>>>(row_start, deg, sorted, wtab + 1 * RELNUM * NHEAD,
                                          hs, hs2, nullptr, nullptr, nullptr, N);
    agg_kernel<2><<<ab, 256, 0, stream>>>(row_start, deg, sorted, wtab + 2 * RELNUM * NHEAD,
                                          hs2, out, centrality, gamma, beta, N);
}